// Round 3
// baseline (1142.565 us; speedup 1.0000x reference)
//
#include <hip/hip_runtime.h>

#define B_ 256
#define D_ 128
#define T_ 1024
#define H_ 64
#define G_ 192
#define TILE_T 64
#define NTILES (T_ / TILE_T)   // 16
#define XGS 65                 // t-stride (padded: 65 % 32 = 1 -> conflict-free)

// Fully fused GRU: one block per batch row, 4 waves.
//   wave 0   : sequential scan, single-wave (no s_barrier in steady state)
//   waves 1-3: GEMM producers, xg tiles -> LDS ring (double buffer)
// Sync via LDS atomic counters (workgroup scope). Producers never hit a
// barrier, so the scan wave is free to run at its own pace.
__global__ __launch_bounds__(256, 1) void gru_fused(
    const float* __restrict__ lat, const float* __restrict__ hidden_init,
    const float* __restrict__ W_ih, const float* __restrict__ W_hh,
    const float* __restrict__ b_ih, const float* __restrict__ b_hh,
    const float* __restrict__ head_w, const float* __restrict__ head_b,
    float* __restrict__ out)
{
    __shared__ float xg_s[2][G_ * XGS];   // [slot][g*XGS + t]  (97.5 KB)
    __shared__ float h_lds[H_];
    __shared__ unsigned prod_done[2];
    __shared__ unsigned cons_done[2];

    const int b    = blockIdx.x;
    const int tid  = threadIdx.x;
    const int lane = tid & 63;
    const int wid  = __builtin_amdgcn_readfirstlane(tid >> 6);

    if (tid < 2) { prod_done[tid] = 0u; cons_done[tid] = 0u; }
    __syncthreads();   // the ONLY workgroup barrier (all 4 waves present)

    if (wid == 0) {
        // ------------------------- consumer: the scan -------------------------
        const int j = lane;
        float4 wr4[16], wz4[16], wn4[16];
        {
            const float4* Wr = (const float4*)(W_hh + (size_t)j * H_);
            const float4* Wz = (const float4*)(W_hh + (size_t)(H_ + j) * H_);
            const float4* Wn = (const float4*)(W_hh + (size_t)(2 * H_ + j) * H_);
#pragma unroll
            for (int q = 0; q < 16; ++q) { wr4[q] = Wr[q]; wz4[q] = Wz[q]; wn4[q] = Wn[q]; }
        }
        const float br = b_hh[j], bz = b_hh[H_ + j], bn = b_hh[2 * H_ + j];
        const float hw = head_w[j];
        float h = hidden_init[b * H_ + j];

        for (int k = 0; k < NTILES; ++k) {
            const int s = k & 1;
            const unsigned tgt = 3u * (unsigned)((k >> 1) + 1);
            while (__hip_atomic_load(&prod_done[s], __ATOMIC_ACQUIRE,
                                     __HIP_MEMORY_SCOPE_WORKGROUP) < tgt)
                __builtin_amdgcn_s_sleep(1);

            const float* xrp = &xg_s[s][(size_t)j * XGS];
            const float* xzp = &xg_s[s][(size_t)(H_ + j) * XGS];
            const float* xnp = &xg_s[s][(size_t)(2 * H_ + j) * XGS];

#pragma unroll 2
            for (int t = 0; t < TILE_T; ++t) {
                float xr = xrp[t];
                float xz = xzp[t];
                float xn = xnp[t];

                h_lds[j] = h;                       // within-wave: DS in-order
                const float4* h4 = (const float4*)h_lds;
                float ar = 0.f, az = 0.f, an = 0.f;
#pragma unroll
                for (int q = 0; q < 16; ++q) {
                    float4 hv = h4[q];              // broadcast read (free)
                    ar = fmaf(wr4[q].x, hv.x, ar); ar = fmaf(wr4[q].y, hv.y, ar);
                    ar = fmaf(wr4[q].z, hv.z, ar); ar = fmaf(wr4[q].w, hv.w, ar);
                    az = fmaf(wz4[q].x, hv.x, az); az = fmaf(wz4[q].y, hv.y, az);
                    az = fmaf(wz4[q].z, hv.z, az); az = fmaf(wz4[q].w, hv.w, az);
                    an = fmaf(wn4[q].x, hv.x, an); an = fmaf(wn4[q].y, hv.y, an);
                    an = fmaf(wn4[q].z, hv.z, an); an = fmaf(wn4[q].w, hv.w, an);
                }
                float r  = __builtin_amdgcn_rcpf(1.f + __expf(-(xr + ar + br)));
                float z  = __builtin_amdgcn_rcpf(1.f + __expf(-(xz + az + bz)));
                float pre = xn + r * (an + bn);
                // tanh(pre) = 1 - 2/(e^{2x}+1); inf/0 limits give +/-1 correctly
                float n  = fmaf(-2.f, __builtin_amdgcn_rcpf(__expf(2.f * pre) + 1.f), 1.f);
                h = (1.f - z) * n + z * h;
            }
            if (lane == 0)
                __hip_atomic_fetch_add(&cons_done[s], 1u, __ATOMIC_RELEASE,
                                       __HIP_MEMORY_SCOPE_WORKGROUP);
        }

        // epilogue: final hidden + head
        out[B_ + b * H_ + j] = h;
        float v = h * hw;
#pragma unroll
        for (int off = 32; off > 0; off >>= 1) v += __shfl_down(v, off);
        if (lane == 0) out[b] = v + head_b[0];
    } else {
        // ----------------------- producers: xg GEMM tiles ----------------------
        const int gw = (wid - 1) * 64;              // this wave's 64 gates
        const float* latb = lat + (size_t)b * (D_ * T_);

        for (int k = 0; k < NTILES; ++k) {
            const int s = k & 1, m = k >> 1;
            if (m >= 1) {
                while (__hip_atomic_load(&cons_done[s], __ATOMIC_ACQUIRE,
                                         __HIP_MEMORY_SCOPE_WORKGROUP) < (unsigned)m)
                    __builtin_amdgcn_s_sleep(1);
            }

            float acc[64];
#pragma unroll
            for (int g = 0; g < 64; ++g) acc[g] = b_ih[gw + g];   // uniform s_load

            const float* latt = latb + k * TILE_T + lane;
            for (int d0 = 0; d0 < D_; d0 += 8) {
                float lv[8];
#pragma unroll
                for (int i = 0; i < 8; ++i) lv[i] = latt[(size_t)(d0 + i) * T_];
#pragma unroll
                for (int g = 0; g < 64; ++g) {
                    const float* wrow = W_ih + (size_t)(gw + g) * D_ + d0;  // uniform
#pragma unroll
                    for (int i = 0; i < 8; ++i)
                        acc[g] = fmaf(lv[i], wrow[i], acc[g]);
                }
            }

            float* xs = xg_s[s];
#pragma unroll
            for (int g = 0; g < 64; ++g)
                xs[(size_t)(gw + g) * XGS + lane] = acc[g];   // 2-way: free
            if (lane == 0)
                __hip_atomic_fetch_add(&prod_done[s], 1u, __ATOMIC_RELEASE,
                                       __HIP_MEMORY_SCOPE_WORKGROUP);
        }
    }
}

extern "C" void kernel_launch(void* const* d_in, const int* in_sizes, int n_in,
                              void* d_out, int out_size, void* d_ws, size_t ws_size,
                              hipStream_t stream)
{
    const float* lat   = (const float*)d_in[0];
    const float* hid0  = (const float*)d_in[1];
    const float* W_ih  = (const float*)d_in[2];
    const float* W_hh  = (const float*)d_in[3];
    const float* b_ih  = (const float*)d_in[4];
    const float* b_hh  = (const float*)d_in[5];
    const float* headw = (const float*)d_in[6];
    const float* headb = (const float*)d_in[7];
    float* out = (float*)d_out;

    gru_fused<<<dim3(B_), dim3(256), 0, stream>>>(
        lat, hid0, W_ih, W_hh, b_ih, b_hh, headw, headb, out);
}